// Round 1
// baseline (942.589 us; speedup 1.0000x reference)
//
#include <hip/hip_runtime.h>

#define BB 256
#define TT 512
#define NN 128
#define GO_IDX 1
#define EOS_IDX 2
#define TSPLIT 496            // bp rows t in [1,TSPLIT) live in LDS; [TSPLIT,512) in d_ws
#define NEGV (-10000.0f)

__global__ __launch_bounds__(256) void viterbi_kernel(
    const float* __restrict__ unaries,   // [B,T,N]
    const float* __restrict__ trans,     // [1,N,N] row-major trans0[cur][prev]
    const int*   __restrict__ lengths_raw, // int32 or int64 (auto-detect)
    float* __restrict__ out,             // [B*T] preds (float) then [B] scores
    unsigned char* __restrict__ ws)      // [B][ (T-TSPLIT)*N ] tail backpointers
{
    __shared__ unsigned char bps[(TSPLIT - 1) * NN];  // 63360 B
    __shared__ __align__(16) float alpha[NN];         // 512 B
    __shared__ float part_best[NN];                   // 512 B
    __shared__ int   part_bp[NN];                     // 512 B
    __shared__ float red_m, red_ls;
    __shared__ float fin_v[2];
    __shared__ int   fin_i[2];

    const int tid  = threadIdx.x;
    const int b    = blockIdx.x;
    const int h    = tid >> 7;        // prev-half: 0 or 1
    const int cur  = tid & 127;       // tag owned by this thread
    const int lane = tid & 63;
    const int wave = tid >> 6;        // 0..3

    // ---- detect int64 vs int32 lengths (lengths >= T/2 = 256 > 0) ----
    int len;
    {
        int probe = lengths_raw[1];   // ==0 iff int64 (high word of lengths[0])
        len = (probe == 0) ? lengths_raw[2 * b] : lengths_raw[b];
    }

    // ---- load this thread's trans chunk into registers: trans0[cur][h*64 + j] ----
    float tr[64];
    {
        const float4* t4 = (const float4*)(trans + cur * NN + h * 64);
#pragma unroll
        for (int i = 0; i < 16; ++i) {
            float4 v = t4[i];
            tr[4*i+0] = v.x; tr[4*i+1] = v.y; tr[4*i+2] = v.z; tr[4*i+3] = v.w;
        }
    }

    // ---- init alpha: log_softmax of [NEG.., 0 at GO, ..NEG] == exact [NEG..,0,..] ----
    if (tid < NN) alpha[tid] = (tid == GO_IDX) ? 0.0f : NEGV;
    __syncthreads();

    const float* ub = unaries + (size_t)b * TT * NN;
    unsigned char* wst = ws + (size_t)b * ((TT - TSPLIT) * NN);

    // ---- distance-2 prefetch pipeline for the unary row ----
    float  u_c = 0.0f, u_n = 0.0f;          // scalar, h==0 threads (their own cur)
    float2 v_c = make_float2(0.f, 0.f);     // packed row, wave 3 (logsumexp owner)
    float2 v_n = make_float2(0.f, 0.f);
    if (h == 0) { u_c = ub[cur]; u_n = ub[NN + cur]; }
    if (wave == 3) {
        const float2* p = (const float2*)ub;
        v_c = p[lane];
        v_n = p[(NN / 2) + lane];
    }

    for (int t = 0; t < len; ++t) {
        // ===== phase 1: max-plus chains over this thread's 64 prevs =====
        float best; int bp;
        {
            const float4* a4 = (const float4*)(alpha + h * 64);
            float bv[4]; int bi[4];
#pragma unroll
            for (int c = 0; c < 4; ++c) {
                bv[c] = -INFINITY; bi[c] = 0;
#pragma unroll
                for (int q = 0; q < 4; ++q) {
                    float4 a = a4[c * 4 + q];
                    const int base = c * 16 + q * 4;
                    float x0 = a.x + tr[base + 0]; if (x0 > bv[c]) { bv[c] = x0; bi[c] = base + 0; }
                    float x1 = a.y + tr[base + 1]; if (x1 > bv[c]) { bv[c] = x1; bi[c] = base + 1; }
                    float x2 = a.z + tr[base + 2]; if (x2 > bv[c]) { bv[c] = x2; bi[c] = base + 2; }
                    float x3 = a.w + tr[base + 3]; if (x3 > bv[c]) { bv[c] = x3; bi[c] = base + 3; }
                }
            }
            // merge ascending: strict > keeps lowest prev on ties (jnp.argmax semantics)
            best = bv[0]; bp = bi[0];
#pragma unroll
            for (int c = 1; c < 4; ++c) { if (bv[c] > best) { best = bv[c]; bp = bi[c]; } }
            bp += h * 64;   // absolute prev index
        }

        if (h == 1) { part_best[cur] = best; part_bp[cur] = bp; }

        // ===== wave 3: logsumexp of unary row t (in-wave, no extra barrier) =====
        if (wave == 3) {
            float m = fmaxf(v_c.x, v_c.y);
#pragma unroll
            for (int off = 32; off; off >>= 1) m = fmaxf(m, __shfl_xor(m, off, 64));
            float s = expf(v_c.x - m) + expf(v_c.y - m);
#pragma unroll
            for (int off = 32; off; off >>= 1) s += __shfl_xor(s, off, 64);
            if (lane == 0) { red_m = m; red_ls = logf(s); }
        }

        // ===== prefetch row t+2 =====
        float  u_nn = 0.0f;
        float2 v_nn = make_float2(0.f, 0.f);
        if (t + 2 < TT) {
            if (h == 0)    u_nn = ub[(t + 2) * NN + cur];
            if (wave == 3) v_nn = ((const float2*)(ub + (t + 2) * NN))[lane];
        }

        __syncthreads();   // partials + logsumexp published

        // ===== phase 2 (h==0): combine halves, update alpha, store bp =====
        if (h == 0) {
            float b1 = part_best[cur]; int p1 = part_bp[cur];
            if (b1 > best) { best = b1; bp = p1; }   // strict >: lower half wins ties
            float p = (u_c - red_m) - red_ls;        // log_softmax, same op order as ref
            alpha[cur] = best + p;
            if (t >= 1) {
                if (t < TSPLIT) bps[(t - 1) * NN + cur] = (unsigned char)bp;
                else            wst[(t - TSPLIT) * NN + cur] = (unsigned char)bp;
            }
        }
        u_c = u_n; u_n = u_nn;
        v_c = v_n; v_n = v_nn;
        __syncthreads();   // alpha published for next step
    }

    __threadfence();       // make global tail-bp writes visible to thread 0

    // ===== terminal: argmax(alpha + trans0[EOS][:]), first-max tie-break =====
    if (h == 0) {
        float v = alpha[cur] + trans[EOS_IDX * NN + cur];
        int idx = cur;
#pragma unroll
        for (int off = 32; off; off >>= 1) {
            float ov = __shfl_xor(v, off, 64);
            int   oi = __shfl_xor(idx, off, 64);
            if (ov > v || (ov == v && oi < idx)) { v = ov; idx = oi; }
        }
        if (lane == 0) { fin_v[wave] = v; fin_i[wave] = idx; }
    }
    __syncthreads();

    // zero-fill masked positions t >= len (disjoint from backtrace range)
    for (int t = len + tid; t < TT; t += 256) out[(size_t)b * TT + t] = 0.0f;

    if (tid == 0) {
        float v0 = fin_v[0], v1 = fin_v[1];
        int   i0 = fin_i[0], i1 = fin_i[1];
        float sc; int tag;
        if (v1 > v0 || (v1 == v0 && i1 < i0)) { sc = v1; tag = i1; }
        else                                  { sc = v0; tag = i0; }
        out[(size_t)BB * TT + b] = sc;

        // serial backtrace: tag[t] = bp[t+1][tag[t+1]]
        for (int t = len - 1; t >= 0; --t) {
            out[(size_t)b * TT + t] = (float)tag;
            if (t >= 1) {
                int nb;
                if (t < TSPLIT) nb = bps[(t - 1) * NN + tag];
                else            nb = ((volatile const unsigned char*)wst)[(t - TSPLIT) * NN + tag];
                tag = nb;
            }
        }
    }
}

extern "C" void kernel_launch(void* const* d_in, const int* in_sizes, int n_in,
                              void* d_out, int out_size, void* d_ws, size_t ws_size,
                              hipStream_t stream) {
    const float* unaries = (const float*)d_in[0];
    const float* trans   = (const float*)d_in[1];
    const int*   lengths = (const int*)d_in[2];
    float* out = (float*)d_out;
    unsigned char* ws = (unsigned char*)d_ws;

    hipLaunchKernelGGL(viterbi_kernel, dim3(BB), dim3(256), 0, stream,
                       unaries, trans, lengths, out, ws);
}

// Round 2
// 673.663 us; speedup vs baseline: 1.3992x; 1.3992x over previous
//
#include <hip/hip_runtime.h>

#define BB 256
#define TT 512
#define NN 128
#define GO_IDX 1
#define EOS_IDX 2
#define TSPLIT 496            // bp rows t in [1,TSPLIT) live in LDS; [TSPLIT,512) in d_ws (proven 524KB)
#define NEGV (-10000.0f)

// ---------- pre-pass: in-place row-wise log_softmax over last dim ----------
// one wave per (b,t) row; reduction order bit-identical to the R1 wave-3 code
__global__ __launch_bounds__(256) void lsm_kernel(float* __restrict__ u) {
    const int wave = threadIdx.x >> 6, lane = threadIdx.x & 63;
    const size_t row = (size_t)blockIdx.x * 4 + wave;
    float2* p = (float2*)(u + row * NN);
    float2 v = p[lane];
    float m = fmaxf(v.x, v.y);
#pragma unroll
    for (int off = 32; off; off >>= 1) m = fmaxf(m, __shfl_xor(m, off, 64));
    float s = expf(v.x - m) + expf(v.y - m);
#pragma unroll
    for (int off = 32; off; off >>= 1) s += __shfl_xor(s, off, 64);
    float ls = logf(s);
    p[lane] = make_float2((v.x - m) - ls, (v.y - m) - ls);
}

// ---------- serial Viterbi: 1 block per batch, 1 barrier per step ----------
__global__ __launch_bounds__(256) void viterbi_kernel(
    const float* __restrict__ probs,     // [B,T,N] already log-softmaxed
    const float* __restrict__ trans,     // [1,N,N] trans0[cur][prev]
    const int*   __restrict__ lengths_raw,
    float* __restrict__ out,             // [B*T] preds then [B] scores
    unsigned char* __restrict__ ws)
{
    __shared__ unsigned char bps[(TSPLIT - 1) * NN];   // 63360 B
    __shared__ __align__(16) float alpha[2][NN];       // double-buffered
    __shared__ float fin_v[2];
    __shared__ int   fin_i[2];

    const int tid  = threadIdx.x;
    const int b    = blockIdx.x;
    const int wave = tid >> 6;
    const int lane = tid & 63;
    const int h    = lane & 1;             // prev-half owned by this lane
    const int cur  = wave * 32 + (lane >> 1);

    int len;
    {
        int probe = lengths_raw[1];        // ==0 iff int64 (lengths >= 256 > 0)
        len = (probe == 0) ? lengths_raw[2 * b] : lengths_raw[b];
    }

    // trans chunk in registers: trans0[cur][h*64 + j]
    float tr[64];
    {
        const float4* t4 = (const float4*)(trans + cur * NN + h * 64);
#pragma unroll
        for (int i = 0; i < 16; ++i) {
            float4 v = t4[i];
            tr[4*i+0] = v.x; tr[4*i+1] = v.y; tr[4*i+2] = v.z; tr[4*i+3] = v.w;
        }
    }

    if (tid < NN) alpha[0][tid] = (tid == GO_IDX) ? 0.0f : NEGV;

    const float* pb = probs + (size_t)b * TT * NN;
    unsigned char* wst = ws + (size_t)b * ((TT - TSPLIT) * NN);

    // 8-deep register window of p[t][cur] (even lanes only)
    float P[8], Nx[8];
    if (h == 0) {
#pragma unroll
        for (int k = 0; k < 8; ++k) P[k] = pb[k * NN + cur];
    }
    __syncthreads();

    const int nG = (len + 7) >> 3;
    for (int g = 0; g < nG; ++g) {
        const int tb = g * 8;
        if (h == 0) {
#pragma unroll
            for (int k = 0; k < 8; ++k) {
                int tt = tb + 8 + k; if (tt > TT - 1) tt = TT - 1;
                Nx[k] = pb[tt * NN + cur];
            }
        }
#pragma unroll
        for (int k = 0; k < 8; ++k) {
            const int t = tb + k;
            if (t < len) {                         // uniform per block
                const float*  ra = alpha[t & 1];
                float*        wa = alpha[(t & 1) ^ 1];
                const float4* a4 = (const float4*)(ra + h * 64);
                float bv[4]; int bi[4];
#pragma unroll
                for (int c = 0; c < 4; ++c) {
                    bv[c] = -INFINITY; bi[c] = 0;
#pragma unroll
                    for (int q = 0; q < 4; ++q) {
                        float4 a = a4[c * 4 + q];
                        const int base = c * 16 + q * 4;
                        float x0 = a.x + tr[base + 0]; if (x0 > bv[c]) { bv[c] = x0; bi[c] = base + 0; }
                        float x1 = a.y + tr[base + 1]; if (x1 > bv[c]) { bv[c] = x1; bi[c] = base + 1; }
                        float x2 = a.z + tr[base + 2]; if (x2 > bv[c]) { bv[c] = x2; bi[c] = base + 2; }
                        float x3 = a.w + tr[base + 3]; if (x3 > bv[c]) { bv[c] = x3; bi[c] = base + 3; }
                    }
                }
                float best = bv[0]; int bp = bi[0];
#pragma unroll
                for (int c = 1; c < 4; ++c) { if (bv[c] > best) { best = bv[c]; bp = bi[c]; } }
                bp += h * 64;
                // pair combine: even lane (prevs 0..63) vs odd lane (64..127); strict > keeps lower prev on ties
                float ob  = __shfl_xor(best, 1, 64);
                int   obp = __shfl_xor(bp, 1, 64);
                if (h == 0) {
                    if (ob > best) { best = ob; bp = obp; }
                    wa[cur] = best + P[k];
                    if (t >= 1) {
                        if (t < TSPLIT) bps[(t - 1) * NN + cur] = (unsigned char)bp;
                        else            wst[(t - TSPLIT) * NN + cur] = (unsigned char)bp;
                    }
                }
                __syncthreads();
            }
        }
#pragma unroll
        for (int k = 0; k < 8; ++k) P[k] = Nx[k];
    }

    __threadfence();   // tail bp global writes visible to thread 0

    // terminal: argmax(alpha + trans0[EOS][:]), first-max tie-break
    if (tid < NN) {
        float v = alpha[len & 1][tid] + trans[EOS_IDX * NN + tid];
        int idx = tid;
#pragma unroll
        for (int off = 32; off; off >>= 1) {
            float ov = __shfl_xor(v, off, 64);
            int   oi = __shfl_xor(idx, off, 64);
            if (ov > v || (ov == v && oi < idx)) { v = ov; idx = oi; }
        }
        if (lane == 0) { fin_v[wave] = v; fin_i[wave] = idx; }
    }
    __syncthreads();

    for (int t = len + tid; t < TT; t += 256) out[(size_t)b * TT + t] = 0.0f;

    if (tid == 0) {
        float v0 = fin_v[0], v1 = fin_v[1];
        int   i0 = fin_i[0], i1 = fin_i[1];
        float sc; int tag;
        if (v1 > v0) { sc = v1; tag = i1; }
        else         { sc = v0; tag = i0; }
        out[(size_t)BB * TT + b] = sc;

        for (int t = len - 1; t >= 0; --t) {
            out[(size_t)b * TT + t] = (float)tag;
            if (t >= 1) {
                int nb;
                if (t < TSPLIT) nb = bps[(t - 1) * NN + tag];
                else            nb = ((volatile const unsigned char*)wst)[(t - TSPLIT) * NN + tag];
                tag = nb;
            }
        }
    }
}

extern "C" void kernel_launch(void* const* d_in, const int* in_sizes, int n_in,
                              void* d_out, int out_size, void* d_ws, size_t ws_size,
                              hipStream_t stream) {
    float*       unaries = (float*)d_in[0];          // transformed in-place to log-softmax
    const float* trans   = (const float*)d_in[1];
    const int*   lengths = (const int*)d_in[2];
    float* out = (float*)d_out;
    unsigned char* ws = (unsigned char*)d_ws;

    // pre-pass: (B*T)/4 rows per block of 4 waves
    hipLaunchKernelGGL(lsm_kernel, dim3((BB * TT) / 4), dim3(256), 0, stream, unaries);
    hipLaunchKernelGGL(viterbi_kernel, dim3(BB), dim3(256), 0, stream,
                       unaries, trans, lengths, out, ws);
}